// Round 3
// baseline (738.061 us; speedup 1.0000x reference)
//
#include <hip/hip_runtime.h>
#include <hip/hip_cooperative_groups.h>
#include <math.h>

namespace cg = cooperative_groups;

#define NLAB 8
#define BATCH 16
// acc layout per batch (floats):
//   [0..27]  emb sums, labels 1..7 x 4 ch
//   [28..34] cnt_k, labels 1..7
//   [35..40] cnt_i, labels 2..7
//   [41..46] agg sums, labels 2..7
#define S_OFF  0
#define CK_OFF 28
#define CI_OFF 35
#define AG_OFF 41
#define ACC_PER_B 48
#define ACC_FLOATS (BATCH * ACC_PER_B)
#define LAB_OFFSET 4096              // fallback path label cache offset
#define GRIDX 128                    // 128x16 = 2048 blocks = exactly 8/CU co-resident

typedef unsigned long long ull;

__device__ __forceinline__ float wrf(float v) {
#pragma unroll
  for (int off = 32; off > 0; off >>= 1) v += __shfl_xor(v, off, 64);
  return v;
}
__device__ __forceinline__ ull wr64(ull v) {
#pragma unroll
  for (int off = 32; off > 0; off >>= 1) v += __shfl_xor(v, off, 64);
  return v;
}

// ===========================================================================
// FUSED cooperative kernel.
// R3 theory: R1 was MLP-starved (41 register accumulators left no VGPRs to
// keep loads in flight); R2 proved delivery scales with outstanding requests
// (4.2 TB/s once scratch traffic existed) but spills ate the win. Fix both:
//  - segment sums accumulate in LDS via native ds_add_f32 (0 VGPRs),
//  - counts in 2 packed u64 (8-bit fields, <=13 per field),
//  - labels kept in a u64 nibble-pack across a grid.sync() -> phase 2 needs
//    ONLY the emb re-read (L3-warm). No labc buffer, no 2nd/3rd launch.
// Live set ~50 VGPR -> fits the (256,8) 64-reg budget WITHOUT spilling.
// ===========================================================================
__global__ __launch_bounds__(256, 8) void k_fused(
    const float4* __restrict__ emb, const int* __restrict__ inst,
    const float* __restrict__ ker, const float* __restrict__ tmk,
    float* __restrict__ acc, float* __restrict__ out, int P)
{
  cg::grid_group grid = cg::this_grid();
  const int b = blockIdx.y;
  const size_t base = (size_t)b * P;
  const float4* e  = emb + base;
  const int*    ip = inst + base;
  const float*  kp = ker + base;
  const float*  tp = tmk + base;

  __shared__ float  s_lds[NLAB][4];   // emb sums (k-gated), label-indexed
  __shared__ float  ck_lds[NLAB];
  __shared__ float  ci_lds[NLAB];
  __shared__ float4 smu[NLAB];
  __shared__ float  agg_lds[NLAB];

  if (threadIdx.x < NLAB * 4) ((float*)s_lds)[threadIdx.x] = 0.f;
  if (threadIdx.x < NLAB) { ck_lds[threadIdx.x] = 0.f; ci_lds[threadIdx.x] = 0.f; }
  __syncthreads();

  const int T   = GRIDX * 256;               // threads per batch row
  const int tid = blockIdx.x * blockDim.x + threadIdx.x;
  const int nfull = P / T;                   // 12 full strided passes (no guard needed)

  ull packs = 0, ck64 = 0, ci64 = 0;

#define P1_BODY(p_, j_) do {                                              \
    float4 ev = e[p_];                                                    \
    int    iv = ip[p_];                                                   \
    float  tv = tp[p_];                                                   \
    float  kv = kp[p_];                                                   \
    int lab = (tv > 0.5f) ? (iv & 7) : 0;                                 \
    int kf  = (kv > 0.5f) ? 1 : 0;                                        \
    packs |= (ull)lab << (4 * (j_));                                      \
    ci64  += 1ull << (8 * lab);                                           \
    ck64  += (ull)kf << (8 * lab);                                        \
    if (kf && lab) {                                                      \
      atomicAdd(&s_lds[lab][0], ev.x);                                    \
      atomicAdd(&s_lds[lab][1], ev.y);                                    \
      atomicAdd(&s_lds[lab][2], ev.z);                                    \
      atomicAdd(&s_lds[lab][3], ev.w);                                    \
    }                                                                     \
  } while (0)

#pragma unroll 4
  for (int j = 0; j < nfull; ++j) {
    int p = tid + j * T;
    P1_BODY(p, j);
  }
  for (int j = nfull; ; ++j) {               // ragged tail (j=12, half the threads)
    int p = tid + j * T;
    if (p >= P) break;
    P1_BODY(p, j);
  }
#undef P1_BODY

  // ---- block reduce: expand 8-bit count fields to 16-bit, wave-reduce u64s
  {
    const ull M8 = 0x00FF00FF00FF00FFull;
    ull ckA = wr64(ck64 & M8);               // even labels, 16-bit slots
    ull ckB = wr64((ck64 >> 8) & M8);        // odd labels
    ull ciA = wr64(ci64 & M8);
    ull ciB = wr64((ci64 >> 8) & M8);
    const int lane = threadIdx.x & 63;
    if (lane == 0) {
#pragma unroll
      for (int f = 0; f < 4; ++f) {
        atomicAdd(&ck_lds[2 * f],     (float)((ckA >> (16 * f)) & 0xFFFF));
        atomicAdd(&ck_lds[2 * f + 1], (float)((ckB >> (16 * f)) & 0xFFFF));
        atomicAdd(&ci_lds[2 * f],     (float)((ciA >> (16 * f)) & 0xFFFF));
        atomicAdd(&ci_lds[2 * f + 1], (float)((ciB >> (16 * f)) & 0xFFFF));
      }
    }
  }
  __syncthreads();
  if (threadIdx.x < AG_OFF) {
    int t = threadIdx.x;
    float v;
    if (t < CK_OFF)      v = s_lds[1 + (t >> 2)][t & 3];
    else if (t < CI_OFF) v = ck_lds[t - CK_OFF + 1];
    else                 v = ci_lds[t - CI_OFF + 2];
    atomicAdd(acc + b * ACC_PER_B + t, v);
  }

  grid.sync();   // ---- all segment sums final; mu computable everywhere ----

  {
    const float* accB = acc + b * ACC_PER_B;
    if (threadIdx.x < NLAB) {
      int l = threadIdx.x;
      float4 m;
      if (l == 0) {
        m = make_float4(0.f, 0.f, 0.f, 0.f);
      } else {
        float inv = 1.f / fmaxf(accB[CK_OFF + l - 1], 1.f);
        m = make_float4(accB[S_OFF + (l - 1) * 4 + 0] * inv,
                        accB[S_OFF + (l - 1) * 4 + 1] * inv,
                        accB[S_OFF + (l - 1) * 4 + 2] * inv,
                        accB[S_OFF + (l - 1) * 4 + 3] * inv);
      }
      smu[l] = m;
      agg_lds[l] = 0.f;
    }
  }
  __syncthreads();

#define P2_BODY(p_, j_) do {                                              \
    int lab = (int)((packs >> (4 * (j_))) & 7);                           \
    if (lab >= 2) {                                                       \
      float4 ev = e[p_];                                                  \
      float4 mv = smu[lab];                                               \
      float dx = ev.x - mv.x, dy = ev.y - mv.y;                           \
      float dz = ev.z - mv.z, dw = ev.w - mv.w;                           \
      float sq = dx * dx + dy * dy + dz * dz + dw * dw;                   \
      float d  = sqrtf(sq);                                               \
      float tt = fmaxf(d - 0.5f, 0.f);                                    \
      float term = logf(fmaf(tt, tt, 1.f));                               \
      atomicAdd(&agg_lds[lab], term);                                     \
    }                                                                     \
  } while (0)

#pragma unroll 4
  for (int j = 0; j < nfull; ++j) {
    int p = tid + j * T;
    P2_BODY(p, j);
  }
  for (int j = nfull; ; ++j) {
    int p = tid + j * T;
    if (p >= P) break;
    P2_BODY(p, j);
  }
#undef P2_BODY

  __syncthreads();
  if (threadIdx.x < 6)
    atomicAdd(acc + b * ACC_PER_B + AG_OFF + threadIdx.x, agg_lds[threadIdx.x + 2]);

  grid.sync();   // ---- agg sums final ----

  // ---- phase 3: finalize in wave 0 of block (0,0) ----
  if (blockIdx.x == 0 && blockIdx.y == 0 && threadIdx.x < 64) {
    const int lane = threadIdx.x;
    float loss = 0.f;
    if (lane < BATCH) {
      const float* a = acc + lane * ACC_PER_B;
      float mu[NLAB][4];
#pragma unroll
      for (int c = 0; c < 4; ++c) mu[0][c] = 0.f;
#pragma unroll
      for (int l = 1; l < NLAB; ++l) {
        float inv = 1.f / fmaxf(a[CK_OFF + l - 1], 1.f);
#pragma unroll
        for (int c = 0; c < 4; ++c) mu[l][c] = a[S_OFF + (l - 1) * 4 + c] * inv;
      }
      float l_agg = 0.f;
#pragma unroll
      for (int l = 2; l < NLAB; ++l)
        l_agg += a[AG_OFF + l - 2] / fmaxf(a[CI_OFF + l - 2], 1.f);
      l_agg *= (1.f / 6.f);
      float ssum = 0.f;
      for (int i = 1; i < NLAB; ++i)
        for (int j = 1; j < NLAB; ++j) {
          if (i == j) continue;
          float dx = mu[i][0] - mu[j][0], dy = mu[i][1] - mu[j][1];
          float dz = mu[i][2] - mu[j][2], dw = mu[i][3] - mu[j][3];
          float dd = sqrtf(dx * dx + dy * dy + dz * dz + dw * dw);
          float t = fmaxf(3.0f - dd, 0.f);
          ssum += logf(fmaf(t, t, 1.f));
        }
      float l_dis = ssum / 42.f;
      float rsum = 0.f;
#pragma unroll
      for (int l = 1; l < NLAB; ++l) {
        float n = sqrtf(mu[l][0] * mu[l][0] + mu[l][1] * mu[l][1] +
                        mu[l][2] * mu[l][2] + mu[l][3] * mu[l][3]);
        rsum += logf(n + 1.f);
      }
      float l_reg = rsum * (0.001f / NLAB);
      loss = l_agg + l_dis + l_reg;
    }
    loss = wrf(loss);
    if (lane == 0) out[0] = loss / (float)BATCH;
  }
}

// ===========================================================================
// Fallback path (R1 three-kernel pipeline) — used only if the cooperative
// launch is rejected by the runtime.
// ===========================================================================
__global__ __launch_bounds__(256, 4) void k_accum(
    const float4* __restrict__ emb, const int* __restrict__ inst,
    const float* __restrict__ ker, const float* __restrict__ tmk,
    float* __restrict__ acc, unsigned char* __restrict__ labc,
    int P, int use_cache)
{
  const int b = blockIdx.y;
  const size_t base = (size_t)b * P;
  const float4* e  = emb + base;
  const int*    ip = inst + base;
  const float*  kp = ker + base;
  const float*  tp = tmk + base;
  unsigned char* lb = labc + base;

  float s[7][4], ck[7], ci[6];
#pragma unroll
  for (int l = 0; l < 7; ++l) {
    ck[l] = 0.f;
    s[l][0] = 0.f; s[l][1] = 0.f; s[l][2] = 0.f; s[l][3] = 0.f;
  }
#pragma unroll
  for (int l = 0; l < 6; ++l) ci[l] = 0.f;

  const int T   = blockDim.x * gridDim.x;
  const int tid = blockIdx.x * blockDim.x + threadIdx.x;

  for (int p0 = tid; p0 < P; p0 += 4 * T) {
    const int p1 = p0 + T, p2 = p0 + 2 * T, p3 = p0 + 3 * T;
    const bool v1 = p1 < P, v2 = p2 < P, v3 = p3 < P;
    const int q1 = v1 ? p1 : p0, q2 = v2 ? p2 : p0, q3 = v3 ? p3 : p0;

    int   i0 = ip[p0], i1 = ip[q1], i2 = ip[q2], i3 = ip[q3];
    float t0v = tp[p0], t1v = tp[q1], t2v = tp[q2], t3v = tp[q3];
    float c0v = kp[p0], c1v = kp[q1], c2v = kp[q2], c3v = kp[q3];
    float4 e0 = e[p0], e1 = e[q1], e2 = e[q2], e3 = e[q3];

    int lab0 = (t0v > 0.5f)       ? (i0 & 7) : 0;
    int lab1 = (v1 && t1v > 0.5f) ? (i1 & 7) : 0;
    int lab2 = (v2 && t2v > 0.5f) ? (i2 & 7) : 0;
    int lab3 = (v3 && t3v > 0.5f) ? (i3 & 7) : 0;
    float k0 = (c0v > 0.5f) ? 1.f : 0.f;
    float k1 = (c1v > 0.5f) ? 1.f : 0.f;
    float k2 = (c2v > 0.5f) ? 1.f : 0.f;
    float k3 = (c3v > 0.5f) ? 1.f : 0.f;

    if (use_cache) {
      lb[p0] = (unsigned char)lab0;
      if (v1) lb[p1] = (unsigned char)lab1;
      if (v2) lb[p2] = (unsigned char)lab2;
      if (v3) lb[p3] = (unsigned char)lab3;
    }

#pragma unroll
    for (int l = 1; l < NLAB; ++l) {
      float m0 = (lab0 == l) ? 1.f : 0.f;
      float m1 = (lab1 == l) ? 1.f : 0.f;
      float m2 = (lab2 == l) ? 1.f : 0.f;
      float m3 = (lab3 == l) ? 1.f : 0.f;
      float mk0 = m0 * k0, mk1 = m1 * k1, mk2 = m2 * k2, mk3 = m3 * k3;
      ck[l - 1] += (mk0 + mk1) + (mk2 + mk3);
      s[l - 1][0] = fmaf(mk0, e0.x, fmaf(mk1, e1.x, fmaf(mk2, e2.x, fmaf(mk3, e3.x, s[l - 1][0]))));
      s[l - 1][1] = fmaf(mk0, e0.y, fmaf(mk1, e1.y, fmaf(mk2, e2.y, fmaf(mk3, e3.y, s[l - 1][1]))));
      s[l - 1][2] = fmaf(mk0, e0.z, fmaf(mk1, e1.z, fmaf(mk2, e2.z, fmaf(mk3, e3.z, s[l - 1][2]))));
      s[l - 1][3] = fmaf(mk0, e0.w, fmaf(mk1, e1.w, fmaf(mk2, e2.w, fmaf(mk3, e3.w, s[l - 1][3]))));
      if (l >= 2) ci[l - 2] += (m0 + m1) + (m2 + m3);
    }
  }

  __shared__ float red[4][48];
  const int wid = threadIdx.x >> 6, lane = threadIdx.x & 63;
#pragma unroll
  for (int l = 0; l < 7; ++l) {
#pragma unroll
    for (int c = 0; c < 4; ++c) {
      float v = wrf(s[l][c]);
      if (lane == 0) red[wid][S_OFF + l * 4 + c] = v;
    }
    float vk = wrf(ck[l]);
    if (lane == 0) red[wid][CK_OFF + l] = vk;
  }
#pragma unroll
  for (int l = 0; l < 6; ++l) {
    float vi = wrf(ci[l]);
    if (lane == 0) red[wid][CI_OFF + l] = vi;
  }
  __syncthreads();
  if (threadIdx.x < AG_OFF) {
    float v = red[0][threadIdx.x] + red[1][threadIdx.x] +
              red[2][threadIdx.x] + red[3][threadIdx.x];
    atomicAdd(acc + b * ACC_PER_B + threadIdx.x, v);
  }
}

__global__ __launch_bounds__(256, 4) void k_agg(
    const float4* __restrict__ emb, const int* __restrict__ inst,
    const float* __restrict__ tmk, const unsigned char* __restrict__ labc,
    float* __restrict__ acc, int P, int use_cache)
{
  const int b = blockIdx.y;
  const size_t base = (size_t)b * P;
  __shared__ float4 smu[NLAB];
  const float* accB = acc + b * ACC_PER_B;
  if (threadIdx.x < NLAB) {
    int l = threadIdx.x;
    float4 m;
    if (l == 0) {
      m = make_float4(0.f, 0.f, 0.f, 0.f);
    } else {
      float inv = 1.f / fmaxf(accB[CK_OFF + l - 1], 1.f);
      m = make_float4(accB[S_OFF + (l - 1) * 4 + 0] * inv,
                      accB[S_OFF + (l - 1) * 4 + 1] * inv,
                      accB[S_OFF + (l - 1) * 4 + 2] * inv,
                      accB[S_OFF + (l - 1) * 4 + 3] * inv);
    }
    smu[l] = m;
  }
  __syncthreads();

  const float4* e = emb + base;
  const unsigned char* lb = labc + base;
  const int*   ip = inst + base;
  const float* tp = tmk + base;

  float aggl[6];
#pragma unroll
  for (int l = 0; l < 6; ++l) aggl[l] = 0.f;

  const int T   = blockDim.x * gridDim.x;
  const int tid = blockIdx.x * blockDim.x + threadIdx.x;

  for (int p0 = tid; p0 < P; p0 += 4 * T) {
    const int p1 = p0 + T, p2 = p0 + 2 * T, p3 = p0 + 3 * T;
    const bool v1 = p1 < P, v2 = p2 < P, v3 = p3 < P;
    const int q1 = v1 ? p1 : p0, q2 = v2 ? p2 : p0, q3 = v3 ? p3 : p0;

    int lab0, lab1, lab2, lab3;
    if (use_cache) {
      lab0 = lb[p0];
      lab1 = v1 ? lb[p1] : 0;
      lab2 = v2 ? lb[p2] : 0;
      lab3 = v3 ? lb[p3] : 0;
    } else {
      int   i0 = ip[p0], i1 = ip[q1], i2 = ip[q2], i3 = ip[q3];
      float t0v = tp[p0], t1v = tp[q1], t2v = tp[q2], t3v = tp[q3];
      lab0 = (t0v > 0.5f)       ? (i0 & 7) : 0;
      lab1 = (v1 && t1v > 0.5f) ? (i1 & 7) : 0;
      lab2 = (v2 && t2v > 0.5f) ? (i2 & 7) : 0;
      lab3 = (v3 && t3v > 0.5f) ? (i3 & 7) : 0;
    }
    float4 e0 = e[p0], e1 = e[q1], e2 = e[q2], e3 = e[q3];

#pragma unroll
    for (int i = 0; i < 4; ++i) {
      int lab = (i == 0) ? lab0 : (i == 1) ? lab1 : (i == 2) ? lab2 : lab3;
      float4 ev = (i == 0) ? e0 : (i == 1) ? e1 : (i == 2) ? e2 : e3;
      float4 mv = smu[lab];
      float dx = ev.x - mv.x, dy = ev.y - mv.y;
      float dz = ev.z - mv.z, dw = ev.w - mv.w;
      float sq = dx * dx + dy * dy + dz * dz + dw * dw;
      float d = sqrtf(sq);
      float t = fmaxf(d - 0.5f, 0.f);
      float term = (lab >= 2) ? logf(fmaf(t, t, 1.f)) : 0.f;
#pragma unroll
      for (int l = 0; l < 6; ++l) aggl[l] += (lab == l + 2) ? term : 0.f;
    }
  }

  __shared__ float red[4][8];
  const int wid = threadIdx.x >> 6, lane = threadIdx.x & 63;
#pragma unroll
  for (int l = 0; l < 6; ++l) {
    float v = wrf(aggl[l]);
    if (lane == 0) red[wid][l] = v;
  }
  __syncthreads();
  if (threadIdx.x < 6) {
    float v = red[0][threadIdx.x] + red[1][threadIdx.x] +
              red[2][threadIdx.x] + red[3][threadIdx.x];
    atomicAdd(acc + b * ACC_PER_B + AG_OFF + threadIdx.x, v);
  }
}

__global__ void k_final(const float* __restrict__ acc, float* __restrict__ out, int nb) {
  const int lane = threadIdx.x;
  float loss = 0.f;
  if (lane < nb) {
    const float* a = acc + lane * ACC_PER_B;
    float mu[NLAB][4];
#pragma unroll
    for (int c = 0; c < 4; ++c) mu[0][c] = 0.f;
#pragma unroll
    for (int l = 1; l < NLAB; ++l) {
      float inv = 1.f / fmaxf(a[CK_OFF + l - 1], 1.f);
#pragma unroll
      for (int c = 0; c < 4; ++c) mu[l][c] = a[S_OFF + (l - 1) * 4 + c] * inv;
    }
    float l_agg = 0.f;
#pragma unroll
    for (int l = 2; l < NLAB; ++l)
      l_agg += a[AG_OFF + l - 2] / fmaxf(a[CI_OFF + l - 2], 1.f);
    l_agg *= (1.f / 6.f);
    float ssum = 0.f;
    for (int i = 1; i < NLAB; ++i)
      for (int j = 1; j < NLAB; ++j) {
        if (i == j) continue;
        float dx = mu[i][0] - mu[j][0], dy = mu[i][1] - mu[j][1];
        float dz = mu[i][2] - mu[j][2], dw = mu[i][3] - mu[j][3];
        float dd = sqrtf(dx * dx + dy * dy + dz * dz + dw * dw);
        float t = fmaxf(3.0f - dd, 0.f);
        ssum += logf(fmaf(t, t, 1.f));
      }
    float l_dis = ssum / 42.f;
    float rsum = 0.f;
#pragma unroll
    for (int l = 1; l < NLAB; ++l) {
      float n = sqrtf(mu[l][0] * mu[l][0] + mu[l][1] * mu[l][1] +
                      mu[l][2] * mu[l][2] + mu[l][3] * mu[l][3]);
      rsum += logf(n + 1.f);
    }
    float l_reg = rsum * (0.001f / NLAB);
    loss = l_agg + l_dis + l_reg;
  }
  loss = wrf(loss);
  if (lane == 0) out[0] = loss / (float)nb;
}

extern "C" void kernel_launch(void* const* d_in, const int* in_sizes, int n_in,
                              void* d_out, int out_size, void* d_ws, size_t ws_size,
                              hipStream_t stream) {
  const float4* emb = (const float4*)d_in[0];
  const int*    inst = (const int*)d_in[1];
  const float*  ker  = (const float*)d_in[2];
  const float*  tmk  = (const float*)d_in[3];
  float* out = (float*)d_out;

  const int total = in_sizes[1];       // B*H*W
  int P = total / BATCH;

  float* acc = (float*)d_ws;

  // d_ws is re-poisoned before every launch — zero the accumulators.
  hipMemsetAsync(d_ws, 0, ACC_FLOATS * sizeof(float), stream);

  // Cooperative fused path: requires label nibble-pack to fit (<=16 px/thread).
  const int T = GRIDX * 256;
  hipError_t cerr = hipErrorUnknown;
  if (P <= 16 * T) {
    void* args[] = {(void*)&emb, (void*)&inst, (void*)&ker, (void*)&tmk,
                    (void*)&acc, (void*)&out, (void*)&P};
    cerr = hipLaunchCooperativeKernel((void*)k_fused, dim3(GRIDX, BATCH),
                                      dim3(256), args, 0, stream);
  }
  if (cerr != hipSuccess) {
    // fallback: R1 three-kernel pipeline
    unsigned char* labc = (unsigned char*)((char*)d_ws + LAB_OFFSET);
    const size_t need = (size_t)LAB_OFFSET + (size_t)total;
    const int use_cache = (ws_size >= need) ? 1 : 0;
    dim3 grid(200, BATCH);
    k_accum<<<grid, 256, 0, stream>>>(emb, inst, ker, tmk, acc, labc, P, use_cache);
    k_agg  <<<grid, 256, 0, stream>>>(emb, inst, tmk, labc, acc, P, use_cache);
    k_final<<<1, 64, 0, stream>>>(acc, out, BATCH);
  }
}

// Round 5
// 241.625 us; speedup vs baseline: 3.0546x; 3.0546x over previous
//
#include <hip/hip_runtime.h>
#include <math.h>

#define NLAB 8
#define BATCH 16
// acc layout per batch (floats):
//   [0..27]  emb sums, labels 1..7 x 4 ch
//   [28..34] cnt_k, labels 1..7
//   [35..40] cnt_i, labels 2..7
//   [41..46] agg sums, labels 2..7
#define S_OFF  0
#define CK_OFF 28
#define CI_OFF 35
#define AG_OFF 41
#define ACC_PER_B 48
#define ACC_FLOATS (BATCH * ACC_PER_B)
#define LAB_OFFSET 4096              // label byte-cache starts here in d_ws
#define GX_ACC 64                    // 64x16 = 1024 blocks = exactly 4/CU @ (256,4)
#define GX_AGG 96                    // 96x16 = 1536 blocks = exactly 6/CU @ (256,6)
#define ILP 8

typedef __attribute__((ext_vector_type(2))) float v2f;

__device__ __forceinline__ v2f v2fma(v2f a, v2f b, v2f c) {
#if defined(__has_builtin) && __has_builtin(__builtin_elementwise_fma)
  return __builtin_elementwise_fma(a, b, c);
#else
  v2f r; r.x = fmaf(a.x, b.x, c.x); r.y = fmaf(a.y, b.y, c.y); return r;
#endif
}

__device__ __forceinline__ float wave_reduce(float v) {
#pragma unroll
  for (int off = 32; off > 0; off >>= 1) v += __shfl_xor(v, off, 64);
  return v;
}

// ---------------------------------------------------------------------------
// Pass 1: per-batch segment sums. R4/R5: force memory-level parallelism.
// R1 evidence: compiler compiled the "batched" loads to VGPR=44 -> only ~2
// loads effectively in flight -> 2.3 TB/s latency-bound (R2 proved the
// system delivers ~3+ TB/s of reads when more requests are outstanding).
// Fix: ILP=8 strided slots; issue 24 meta loads then 8 emb float4 loads,
// then sched_barrier(0) so no consume is hoisted above the load batch and
// the allocator must keep ~56 load-dest VGPRs live (one partial-vmcnt wait,
// 32 loads outstanding = ~14 KB/wave in flight).
// Accumulators packed as channel-pair v2f -> v_pk_fma_f32 (half the VALU).
// ---------------------------------------------------------------------------
__global__ __launch_bounds__(256, 4) void k_accum(
    const float4* __restrict__ emb, const int* __restrict__ inst,
    const float* __restrict__ ker, const float* __restrict__ tmk,
    float* __restrict__ acc, unsigned char* __restrict__ labc,
    int P, int use_cache)
{
  const int b = blockIdx.y;
  const size_t base = (size_t)b * P;
  const float4* e  = emb + base;
  const int*    ip = inst + base;
  const float*  kp = ker + base;
  const float*  tp = tmk + base;
  unsigned char* lb = labc + base;

  // s2[j][0]=(ch0,ch1), s2[j][1]=(ch2,ch3) for label j+1; cnt2[j]=(ck,ci)
  v2f s2[7][2], cnt2[7];
#pragma unroll
  for (int j = 0; j < 7; ++j) {
    s2[j][0] = (v2f)(0.f);
    s2[j][1] = (v2f)(0.f);
    cnt2[j]  = (v2f)(0.f);
  }

  const int T   = blockDim.x * gridDim.x;     // 16384 threads per batch row
  const int tid = blockIdx.x * blockDim.x + threadIdx.x;

  int p0 = tid;
  for (; p0 + (ILP - 1) * T < P; p0 += ILP * T) {
    int   iv[ILP]; float tv[ILP], kv[ILP]; float4 ev[ILP];
    // meta loads first, emb last: decode waits on meta via partial vmcnt
    // while the 8 dwordx4 emb loads remain outstanding.
#pragma unroll
    for (int k = 0; k < ILP; ++k) iv[k] = ip[p0 + k * T];
#pragma unroll
    for (int k = 0; k < ILP; ++k) tv[k] = tp[p0 + k * T];
#pragma unroll
    for (int k = 0; k < ILP; ++k) kv[k] = kp[p0 + k * T];
#pragma unroll
    for (int k = 0; k < ILP; ++k) ev[k] = e[p0 + k * T];
    __builtin_amdgcn_sched_barrier(0);

    int lab[ILP]; float kf[ILP];
#pragma unroll
    for (int k = 0; k < ILP; ++k) {
      lab[k] = (tv[k] > 0.5f) ? (iv[k] & 7) : 0;
      kf[k]  = (kv[k] > 0.5f) ? 1.f : 0.f;
      if (use_cache) lb[p0 + k * T] = (unsigned char)lab[k];
    }

#pragma unroll
    for (int l = 1; l < NLAB; ++l) {
#pragma unroll
      for (int k = 0; k < ILP; ++k) {
        float m  = (lab[k] == l) ? 1.f : 0.f;
        float mk = m * kf[k];
        v2f mk2; mk2.x = mk; mk2.y = mk;
        v2f e01; e01.x = ev[k].x; e01.y = ev[k].y;
        v2f e23; e23.x = ev[k].z; e23.y = ev[k].w;
        v2f cm;  cm.x = mk; cm.y = m;
        s2[l - 1][0] = v2fma(mk2, e01, s2[l - 1][0]);
        s2[l - 1][1] = v2fma(mk2, e23, s2[l - 1][1]);
        cnt2[l - 1] += cm;
      }
    }
  }
  // scalar tail (<= ILP-1 pixels per thread)
  for (int p = p0; p < P; p += T) {
    int   iv = ip[p];
    float tv = tp[p];
    float kv = kp[p];
    float4 ev = e[p];
    int lab = (tv > 0.5f) ? (iv & 7) : 0;
    float kf = (kv > 0.5f) ? 1.f : 0.f;
    if (use_cache) lb[p] = (unsigned char)lab;
#pragma unroll
    for (int l = 1; l < NLAB; ++l) {
      float m  = (lab == l) ? 1.f : 0.f;
      float mk = m * kf;
      v2f mk2; mk2.x = mk; mk2.y = mk;
      v2f e01; e01.x = ev.x; e01.y = ev.y;
      v2f e23; e23.x = ev.z; e23.y = ev.w;
      v2f cm;  cm.x = mk; cm.y = m;
      s2[l - 1][0] = v2fma(mk2, e01, s2[l - 1][0]);
      s2[l - 1][1] = v2fma(mk2, e23, s2[l - 1][1]);
      cnt2[l - 1] += cm;
    }
  }

  // block-level reduction: wave_reduce -> LDS -> one atomic per block per slot
  __shared__ float red[4][48];
  const int wid = threadIdx.x >> 6, lane = threadIdx.x & 63;
#pragma unroll
  for (int j = 0; j < 7; ++j) {
    float v0 = wave_reduce(s2[j][0].x);
    float v1 = wave_reduce(s2[j][0].y);
    float v2 = wave_reduce(s2[j][1].x);
    float v3 = wave_reduce(s2[j][1].y);
    float vk = wave_reduce(cnt2[j].x);
    if (lane == 0) {
      red[wid][S_OFF + j * 4 + 0] = v0;
      red[wid][S_OFF + j * 4 + 1] = v1;
      red[wid][S_OFF + j * 4 + 2] = v2;
      red[wid][S_OFF + j * 4 + 3] = v3;
      red[wid][CK_OFF + j] = vk;
    }
    if (j >= 1) {
      float vi = wave_reduce(cnt2[j].y);
      if (lane == 0) red[wid][CI_OFF + (j - 1)] = vi;
    }
  }
  __syncthreads();
  if (threadIdx.x < AG_OFF) {
    float v = red[0][threadIdx.x] + red[1][threadIdx.x] +
              red[2][threadIdx.x] + red[3][threadIdx.x];
    atomicAdd(acc + b * ACC_PER_B + threadIdx.x, v);
  }
}

// ---------------------------------------------------------------------------
// Pass 2: aggregation term vs mu, labels 2..7. Same forced-MLP structure,
// (256,6): live set ~60 VGPR fits the 85-reg budget -> 24 waves/CU.
// ---------------------------------------------------------------------------
__global__ __launch_bounds__(256, 6) void k_agg(
    const float4* __restrict__ emb, const int* __restrict__ inst,
    const float* __restrict__ tmk, const unsigned char* __restrict__ labc,
    float* __restrict__ acc, int P, int use_cache)
{
  const int b = blockIdx.y;
  const size_t base = (size_t)b * P;
  __shared__ float4 smu[NLAB];
  const float* accB = acc + b * ACC_PER_B;
  if (threadIdx.x < NLAB) {
    int l = threadIdx.x;
    float4 m;
    if (l == 0) {
      m = make_float4(0.f, 0.f, 0.f, 0.f);
    } else {
      float inv = 1.f / fmaxf(accB[CK_OFF + l - 1], 1.f);
      m = make_float4(accB[S_OFF + (l - 1) * 4 + 0] * inv,
                      accB[S_OFF + (l - 1) * 4 + 1] * inv,
                      accB[S_OFF + (l - 1) * 4 + 2] * inv,
                      accB[S_OFF + (l - 1) * 4 + 3] * inv);
    }
    smu[l] = m;
  }
  __syncthreads();

  const float4* e = emb + base;
  const unsigned char* lb = labc + base;
  const int*   ip = inst + base;
  const float* tp = tmk + base;

  float aggl[6];
#pragma unroll
  for (int l = 0; l < 6; ++l) aggl[l] = 0.f;

  const int T   = blockDim.x * gridDim.x;     // 24576 threads per batch row
  const int tid = blockIdx.x * blockDim.x + threadIdx.x;

  int p0 = tid;
  for (; p0 + (ILP - 1) * T < P; p0 += ILP * T) {
    int lab[ILP]; float4 ev[ILP];
    if (use_cache) {
#pragma unroll
      for (int k = 0; k < ILP; ++k) lab[k] = lb[p0 + k * T];
    } else {
      int iv[ILP]; float tv[ILP];
#pragma unroll
      for (int k = 0; k < ILP; ++k) iv[k] = ip[p0 + k * T];
#pragma unroll
      for (int k = 0; k < ILP; ++k) tv[k] = tp[p0 + k * T];
#pragma unroll
      for (int k = 0; k < ILP; ++k) lab[k] = (tv[k] > 0.5f) ? (iv[k] & 7) : 0;
    }
#pragma unroll
    for (int k = 0; k < ILP; ++k) ev[k] = e[p0 + k * T];
    __builtin_amdgcn_sched_barrier(0);

#pragma unroll
    for (int k = 0; k < ILP; ++k) {
      float4 mv = smu[lab[k]];
      float dx = ev[k].x - mv.x, dy = ev[k].y - mv.y;
      float dz = ev[k].z - mv.z, dw = ev[k].w - mv.w;
      float sq = dx * dx + dy * dy + dz * dz + dw * dw;
      float d  = sqrtf(sq);
      float t  = fmaxf(d - 0.5f, 0.f);                 // DELTA_V
      float term = (lab[k] >= 2) ? logf(fmaf(t, t, 1.f)) : 0.f;
#pragma unroll
      for (int l = 0; l < 6; ++l) aggl[l] += (lab[k] == l + 2) ? term : 0.f;
    }
  }
  for (int p = p0; p < P; p += T) {
    int lab;
    if (use_cache) lab = lb[p];
    else           lab = (tp[p] > 0.5f) ? (ip[p] & 7) : 0;
    float4 ev = e[p];
    float4 mv = smu[lab];
    float dx = ev.x - mv.x, dy = ev.y - mv.y;
    float dz = ev.z - mv.z, dw = ev.w - mv.w;
    float d = sqrtf(dx * dx + dy * dy + dz * dz + dw * dw);
    float t = fmaxf(d - 0.5f, 0.f);
    float term = (lab >= 2) ? logf(fmaf(t, t, 1.f)) : 0.f;
#pragma unroll
    for (int l = 0; l < 6; ++l) aggl[l] += (lab == l + 2) ? term : 0.f;
  }

  __shared__ float red[4][8];
  const int wid = threadIdx.x >> 6, lane = threadIdx.x & 63;
#pragma unroll
  for (int l = 0; l < 6; ++l) {
    float v = wave_reduce(aggl[l]);
    if (lane == 0) red[wid][l] = v;
  }
  __syncthreads();
  if (threadIdx.x < 6) {
    float v = red[0][threadIdx.x] + red[1][threadIdx.x] +
              red[2][threadIdx.x] + red[3][threadIdx.x];
    atomicAdd(acc + b * ACC_PER_B + AG_OFF + threadIdx.x, v);
  }
}

// ---------------------------------------------------------------------------
// Finalize: one wave; lane b handles batch b, then wave-reduce the batch mean.
// ---------------------------------------------------------------------------
__global__ void k_final(const float* __restrict__ acc, float* __restrict__ out, int nb) {
  const int lane = threadIdx.x;
  float loss = 0.f;
  if (lane < nb) {
    const float* a = acc + lane * ACC_PER_B;
    float mu[NLAB][4];
#pragma unroll
    for (int c = 0; c < 4; ++c) mu[0][c] = 0.f;
#pragma unroll
    for (int l = 1; l < NLAB; ++l) {
      float inv = 1.f / fmaxf(a[CK_OFF + l - 1], 1.f);
#pragma unroll
      for (int c = 0; c < 4; ++c) mu[l][c] = a[S_OFF + (l - 1) * 4 + c] * inv;
    }
    // l_agg = mean over labels 2..7 of agg_sum / max(cnt_i,1)
    float l_agg = 0.f;
#pragma unroll
    for (int l = 2; l < NLAB; ++l)
      l_agg += a[AG_OFF + l - 2] / fmaxf(a[CI_OFF + l - 2], 1.f);
    l_agg *= (1.f / 6.f);
    // l_dis over ordered pairs i!=j, i,j in 1..7 (42 pairs)
    float ssum = 0.f;
    for (int i = 1; i < NLAB; ++i)
      for (int j = 1; j < NLAB; ++j) {
        if (i == j) continue;
        float dx = mu[i][0] - mu[j][0], dy = mu[i][1] - mu[j][1];
        float dz = mu[i][2] - mu[j][2], dw = mu[i][3] - mu[j][3];
        float dd = sqrtf(dx * dx + dy * dy + dz * dz + dw * dw);
        float t = fmaxf(3.0f - dd, 0.f);         // 2*DELTA_D
        ssum += logf(fmaf(t, t, 1.f));
      }
    float l_dis = ssum / 42.f;
    // l_reg: mu[0]=0 contributes log(1)=0; mean over all 8 labels
    float rsum = 0.f;
#pragma unroll
    for (int l = 1; l < NLAB; ++l) {
      float n = sqrtf(mu[l][0] * mu[l][0] + mu[l][1] * mu[l][1] +
                      mu[l][2] * mu[l][2] + mu[l][3] * mu[l][3]);
      rsum += logf(n + 1.f);
    }
    float l_reg = rsum * (0.001f / NLAB);
    loss = l_agg + l_dis + l_reg;
  }
  loss = wave_reduce(loss);
  if (lane == 0) out[0] = loss / (float)nb;      // LOSS_WEIGHT = 1
}

extern "C" void kernel_launch(void* const* d_in, const int* in_sizes, int n_in,
                              void* d_out, int out_size, void* d_ws, size_t ws_size,
                              hipStream_t stream) {
  const float4* emb = (const float4*)d_in[0];
  const int*    inst = (const int*)d_in[1];
  const float*  ker  = (const float*)d_in[2];
  const float*  tmk  = (const float*)d_in[3];
  float* out = (float*)d_out;

  const int total = in_sizes[1];       // B*H*W
  const int P = total / BATCH;

  float* acc = (float*)d_ws;
  unsigned char* labc = (unsigned char*)((char*)d_ws + LAB_OFFSET);
  const size_t need = (size_t)LAB_OFFSET + (size_t)total;   // 1 byte per pixel
  const int use_cache = (ws_size >= need) ? 1 : 0;

  // d_ws is re-poisoned to 0xAA before every launch — zero the accumulators.
  hipMemsetAsync(d_ws, 0, ACC_FLOATS * sizeof(float), stream);

  k_accum<<<dim3(GX_ACC, BATCH), 256, 0, stream>>>(emb, inst, ker, tmk, acc, labc, P, use_cache);
  k_agg  <<<dim3(GX_AGG, BATCH), 256, 0, stream>>>(emb, inst, tmk, labc, acc, P, use_cache);
  k_final<<<1, 64, 0, stream>>>(acc, out, BATCH);
}